// Round 1
// 1850.627 us; speedup vs baseline: 5.4023x; 5.4023x over previous
//
#include <hip/hip_runtime.h>

// PCRNN: S=256 B=16 V=32000 E=512 H=1024.
// Pipeline: gather+cvt -> GEMM1 (fp16 MFMA) -> fp32 recurrence (fence-free
//           flag sync via agent-scope atomics) -> GEMM3 (fp16 MFMA + bias).

typedef _Float16 half8 __attribute__((ext_vector_type(8)));
typedef _Float16 half4 __attribute__((ext_vector_type(4)));
typedef float    f32x4 __attribute__((ext_vector_type(4)));

#define S_  256
#define B_  16
#define V_  32000
#define E_  512
#define H_  1024
#define M_  4096   // S_*B_

// ---------- async global->LDS staging (16B per lane) ----------
__device__ __forceinline__ void stage16(const _Float16* g, _Float16* l) {
#if __has_builtin(__builtin_amdgcn_global_load_lds)
  __builtin_amdgcn_global_load_lds(
      (const __attribute__((address_space(1))) void*)g,
      (__attribute__((address_space(3))) void*)l, 16, 0, 0);
#else
  *(half8*)l = *(const half8*)g;
#endif
}

// ---------- fp32 -> fp16 convert ----------
__global__ __launch_bounds__(256) void cvt16(const float* __restrict__ s,
                                             _Float16* __restrict__ d, long n4) {
  long i = (long)blockIdx.x * 256 + threadIdx.x;
  if (i < n4) {
    f32x4 v = *(const f32x4*)(s + i * 4);
    half4 o = { (_Float16)v.x, (_Float16)v.y, (_Float16)v.z, (_Float16)v.w };
    *(half4*)(d + i * 4) = o;
  }
}

// ---------- embedding gather + fp16 cast: A1[r][e] = emb[tok[r]][e] ----------
__global__ __launch_bounds__(256) void gather_emb(const int* __restrict__ tok,
                                                  const float* __restrict__ emb,
                                                  _Float16* __restrict__ A1) {
  int r = blockIdx.x;               // 0..4095  (r = s*B + b)
  int t = tok[r];
  const float* src = emb + (long)t * E_;
  _Float16* dst = A1 + (long)r * E_;
  int e = threadIdx.x * 2;
  float2 v = *(const float2*)(src + e);
  dst[e]     = (_Float16)v.x;
  dst[e + 1] = (_Float16)v.y;
}

// ---------- fp16 MFMA GEMM: C[M,N] = A[M,K] @ B[N,K]^T (+bias) ----------
// 128x128 tile, BK=32, 256 thr (4 waves in 2x2 of 64x64), 16x16x32 MFMA.
template <bool BIAS>
__global__ __launch_bounds__(256, 2) void gemm_tn(const _Float16* __restrict__ A,
                                                  const _Float16* __restrict__ B,
                                                  const float* __restrict__ bias,
                                                  float* __restrict__ C,
                                                  int M, int N, int K) {
  __shared__ __align__(16) _Float16 As[128 * 32];
  __shared__ __align__(16) _Float16 Bs[128 * 32];

  const int tid  = threadIdx.x;
  const int m0   = blockIdx.x * 128;
  const int n0   = blockIdx.y * 128;
  const int wave = tid >> 6;
  const int lane = tid & 63;
  const int wm   = (wave >> 1) * 64;
  const int wn   = (wave & 1) * 64;
  const int lr   = lane & 15;   // m (A) / n (B) index within 16
  const int lq   = lane >> 4;   // k-quad

  const int srow = tid >> 2;
  const int skof = (tid & 3) * 8;
  const _Float16* ag0 = A + (long)(m0 + srow) * K + skof;
  const _Float16* ag1 = A + (long)(m0 + 64 + srow) * K + skof;
  const _Float16* bg0 = B + (long)(n0 + srow) * K + skof;
  const _Float16* bg1 = B + (long)(n0 + 64 + srow) * K + skof;
  _Float16* la0 = As + tid * 8;
  _Float16* la1 = As + 2048 + tid * 8;
  _Float16* lb0 = Bs + tid * 8;
  _Float16* lb1 = Bs + 2048 + tid * 8;

  f32x4 acc[4][4];
  const f32x4 vz = {0.f, 0.f, 0.f, 0.f};
#pragma unroll
  for (int i = 0; i < 4; ++i)
#pragma unroll
    for (int j = 0; j < 4; ++j) acc[i][j] = vz;

  const _Float16* pa = As + (wm + lr) * 32 + lq * 8;
  const _Float16* pb = Bs + (wn + lr) * 32 + lq * 8;

  for (int k0 = 0; k0 < K; k0 += 32) {
    __syncthreads();                       // LDS free (prev iter reads done)
    stage16(ag0, la0); stage16(ag1, la1);
    stage16(bg0, lb0); stage16(bg1, lb1);
    ag0 += 32; ag1 += 32; bg0 += 32; bg1 += 32;
    __syncthreads();                       // drains vmcnt: LDS filled

    half8 af[4], bf[4];
#pragma unroll
    for (int i = 0; i < 4; ++i) af[i] = *(const half8*)(pa + i * 16 * 32);
#pragma unroll
    for (int j = 0; j < 4; ++j) bf[j] = *(const half8*)(pb + j * 16 * 32);
#pragma unroll
    for (int i = 0; i < 4; ++i)
#pragma unroll
      for (int j = 0; j < 4; ++j)
        acc[i][j] = __builtin_amdgcn_mfma_f32_16x16x32_f16(af[i], bf[j], acc[i][j], 0, 0, 0);
  }

  // epilogue: C/D layout col=lane&15, row=(lane>>4)*4+reg
  const int cm = m0 + wm + lq * 4;
  const int cn = n0 + wn + lr;
#pragma unroll
  for (int j = 0; j < 4; ++j) {
    const int col = cn + j * 16;
    const float bj = BIAS ? bias[col] : 0.f;
#pragma unroll
    for (int i = 0; i < 4; ++i) {
      float* cp = C + (long)(cm + i * 16) * N + col;
#pragma unroll
      for (int r = 0; r < 4; ++r) cp[(long)r * N] = acc[i][j][r] + bj;
    }
  }
}

// ---------- recurrence ----------
// 256 WGs = 8 teams (batch pair each) x 32 slices (32 W_hh rows each, in VGPRs).
// FENCE-FREE cross-WG sync: t_all and flags are communicated exclusively via
// RELAXED AGENT-scope atomics, which execute at the coherence point (bypassing
// the non-coherent per-XCD L2s). Producer orders data-before-flag with a single
// s_waitcnt vmcnt(0) in the producing wave. No __threadfence() => no per-step
// L2 writeback/invalidate ops (those serialized ~32 WGs/XCD and were ~35us/step).
// Pollers are wave 1 so they overlap with wave 0's store+signal of the prior step.
__global__ __launch_bounds__(256, 1) void recurrence(const float* __restrict__ Whh,
                                                     const float* __restrict__ x,
                                                     float* __restrict__ t_all,
                                                     _Float16* __restrict__ A3,
                                                     int* __restrict__ flags) {
  const int g     = blockIdx.x;
  const int team  = g & 7;
  const int slice = g >> 3;
  const int tid   = threadIdx.x;
  const int jl    = tid & 31;   // row within slice
  const int ks    = tid >> 5;   // 0..7, 128-wide k slice
  const int j     = slice * 32 + jl;
  const int b0    = team * 2;

  __shared__ __align__(16) float tld[2][H_];
  __shared__ float part[8][2][32];

  // W_hh rows in registers: thread owns W[j][ks*128 .. ks*128+128)
  f32x4 w[32];
  {
    const float* wp = Whh + (long)j * H_ + ks * 128;
#pragma unroll
    for (int q = 0; q < 32; ++q) w[q] = *(const f32x4*)(wp + q * 4);
  }

  // ---- step 0: t0 = tanh(x[0]) ----
  if (tid < 64) {
    int b = tid >> 5, jj = slice * 32 + (tid & 31);
    float h  = x[(long)(b0 + b) * H_ + jj];
    float tt = tanhf(h);
    __hip_atomic_store(&t_all[(long)(b0 + b) * H_ + jj], tt,
                       __ATOMIC_RELAXED, __HIP_MEMORY_SCOPE_AGENT);
    A3[(long)(b0 + b) * H_ + jj] = (_Float16)tt;
    asm volatile("s_waitcnt vmcnt(0)" ::: "memory");   // t stores globally visible
    if (tid == 0)
      __hip_atomic_store(&flags[g], 1, __ATOMIC_RELAXED, __HIP_MEMORY_SCOPE_AGENT);
  }

  for (int s = 1; s < S_; ++s) {
    // prefetch x[s] early (independent of flags; stays L2-cached — no invalidates)
    float xr = 0.f;
    if (tid < 64)
      xr = x[((long)s * B_ + b0 + (tid >> 5)) * H_ + slice * 32 + (tid & 31)];

    // wave 1 polls our team's 32 producers of step s-1 (overlaps wave 0's signal)
    if (tid >= 64 && tid < 96) {
      const int* fp = &flags[(s - 1) * 256 + ((tid & 31) << 3) + team];
      while (__hip_atomic_load(fp, __ATOMIC_RELAXED, __HIP_MEMORY_SCOPE_AGENT) == 0)
        __builtin_amdgcn_s_sleep(1);
    }
    __syncthreads();

    // stage t_prev rows (b0, b0+1): 2048 floats = 1024 x 8B agent-scope loads
    {
      const unsigned long long* tp =
          (const unsigned long long*)(t_all + ((long)(s - 1) * B_ + b0) * H_);
      unsigned long long v0 = __hip_atomic_load(tp + tid,       __ATOMIC_RELAXED, __HIP_MEMORY_SCOPE_AGENT);
      unsigned long long v1 = __hip_atomic_load(tp + tid + 256, __ATOMIC_RELAXED, __HIP_MEMORY_SCOPE_AGENT);
      unsigned long long v2 = __hip_atomic_load(tp + tid + 512, __ATOMIC_RELAXED, __HIP_MEMORY_SCOPE_AGENT);
      unsigned long long v3 = __hip_atomic_load(tp + tid + 768, __ATOMIC_RELAXED, __HIP_MEMORY_SCOPE_AGENT);
      unsigned long long* dst = (unsigned long long*)&tld[0][0];
      dst[tid]       = v0;
      dst[tid + 256] = v1;
      dst[tid + 512] = v2;
      dst[tid + 768] = v3;
    }
    __syncthreads();

    float a0 = 0.f, a1 = 0.f;
    const f32x4* t0p = (const f32x4*)&tld[0][ks * 128];
    const f32x4* t1p = (const f32x4*)&tld[1][ks * 128];
#pragma unroll
    for (int q = 0; q < 32; ++q) {
      f32x4 wv = w[q], u0 = t0p[q], u1 = t1p[q];
      a0 += wv.x * u0.x; a0 += wv.y * u0.y; a0 += wv.z * u0.z; a0 += wv.w * u0.w;
      a1 += wv.x * u1.x; a1 += wv.y * u1.y; a1 += wv.z * u1.z; a1 += wv.w * u1.w;
    }
    part[ks][0][jl] = a0;
    part[ks][1][jl] = a1;
    __syncthreads();

    // finish + signal: wave 0 only — other waves run ahead to next step's poll
    if (tid < 64) {
      int b = tid >> 5, jj = slice * 32 + (tid & 31);
      float h = xr;
#pragma unroll
      for (int k2 = 0; k2 < 8; ++k2) h += part[k2][b][tid & 31];
      float tt = tanhf(h);
      __hip_atomic_store(&t_all[((long)s * B_ + b0 + b) * H_ + jj], tt,
                         __ATOMIC_RELAXED, __HIP_MEMORY_SCOPE_AGENT);
      A3[((long)s * B_ + b0 + b) * H_ + jj] = (_Float16)tt;
      asm volatile("s_waitcnt vmcnt(0)" ::: "memory");   // t stores at coherence point
      if (tid == 0)
        __hip_atomic_store(&flags[s * 256 + g], 1,
                           __ATOMIC_RELAXED, __HIP_MEMORY_SCOPE_AGENT);
    }
  }
}

// ---------------------------------------------------------------------------
extern "C" void kernel_launch(void* const* d_in, const int* in_sizes, int n_in,
                              void* d_out, int out_size, void* d_ws, size_t ws_size,
                              hipStream_t stream) {
  const int*   tok  = (const int*)d_in[0];    // [S,B] -> flat r = s*B+b
  const float* emb  = (const float*)d_in[1];  // [V,E]
  const float* Win  = (const float*)d_in[2];  // [H,E]
  const float* Whh  = (const float*)d_in[3];  // [H,H]
  const float* Wout = (const float*)d_in[4];  // [V,H]
  const float* bout = (const float*)d_in[5];  // [V]
  float* out = (float*)d_out;                 // [S*B, V]

  char* ws = (char*)d_ws;
  _Float16* A1    = (_Float16*)ws; ws += (long)M_ * E_ * 2;   //  4.19 MB
  _Float16* W16in = (_Float16*)ws; ws += (long)H_ * E_ * 2;   //  1.05 MB
  _Float16* W16o  = (_Float16*)ws; ws += (long)V_ * H_ * 2;   // 65.54 MB
  float*    x     = (float*)ws;    ws += (long)M_ * H_ * 4;   // 16.78 MB
  float*    t_all = (float*)ws;    ws += (long)M_ * H_ * 4;   // 16.78 MB
  _Float16* A3    = (_Float16*)ws; ws += (long)M_ * H_ * 2;   //  8.39 MB
  int*      flags = (int*)ws;      ws += (long)S_ * 256 * 4;  //  0.26 MB

  hipMemsetAsync(flags, 0, (long)S_ * 256 * 4, stream);

  gather_emb<<<M_, 256, 0, stream>>>(tok, emb, A1);

  long n4_in = (long)H_ * E_ / 4;
  cvt16<<<(int)((n4_in + 255) / 256), 256, 0, stream>>>(Win, W16in, n4_in);
  long n4_o = (long)V_ * H_ / 4;
  cvt16<<<(int)((n4_o + 255) / 256), 256, 0, stream>>>(Wout, W16o, n4_o);

  // x = A1 @ W_in^T : [4096,512] x [1024,512]^T
  gemm_tn<false><<<dim3(M_ / 128, H_ / 128), 256, 0, stream>>>(
      A1, W16in, nullptr, x, M_, H_, E_);

  // recurrence (cooperative: guarantees all 256 WGs co-resident for flag sync)
  {
    void* args[] = {(void*)&Whh, (void*)&x, (void*)&t_all, (void*)&A3, (void*)&flags};
    hipLaunchCooperativeKernel((void*)recurrence, dim3(256), dim3(256), args, 0, stream);
  }

  // logits = A3 @ W_out^T + b : [4096,1024] x [32000,1024]^T
  gemm_tn<true><<<dim3(M_ / 128, V_ / 128), 256, 0, stream>>>(
      A3, W16o, bout, out, M_, V_, H_);
}